// Round 3
// baseline (951.996 us; speedup 1.0000x reference)
//
#include <hip/hip_runtime.h>

// ---------- types / helpers ----------
typedef __attribute__((ext_vector_type(8))) short short8;
typedef __attribute__((ext_vector_type(4))) float f32x4;

__device__ __forceinline__ short f2bf(float f) {
    unsigned u = __builtin_bit_cast(unsigned, f);
    u = (u + 0x7FFFu + ((u >> 16) & 1u)) >> 16;
    return (short)u;
}
__device__ __forceinline__ float bf2f(short h) {
    unsigned u = ((unsigned)(unsigned short)h) << 16;
    return __builtin_bit_cast(float, u);
}
// pack two f32 -> two bf16 in one dword (round-half-up + v_perm)
__device__ __forceinline__ unsigned pkbf2(float lo, float hi) {
    unsigned ul = __builtin_bit_cast(unsigned, lo) + 0x8000u;
    unsigned uh = __builtin_bit_cast(unsigned, hi) + 0x8000u;
    return __builtin_amdgcn_perm(uh, ul, 0x07060302);
}
#define WAVE_LDS_FENCE() asm volatile("s_waitcnt lgkmcnt(0)" ::: "memory")

// ws layout (bytes)
#define OFF_W1T 0L            // 256*64*2  = 32768
#define OFF_W2T 32768L        // 64*128*2  = 16384
#define OFF_W3T 49152L        // 256*64*2  = 32768
#define OFF_W4T 81920L        // 64*128*2  = 16384
#define OFF_WATT 98304L       // 8*128*4   = 4096
#define OFF_GPART 102400L     // 16384*64*4 = 4194304
#define OFF_GPART2 4296704L   // 8*16*128*4 = 65536
#define OFF_T 4362240L        // 524288*128*2 = 134217728

// ---------- K0: weight transpose + bf16 cast ----------
__global__ __launch_bounds__(256) void k_prep(
    const float* __restrict__ w1, const float* __restrict__ w2,
    const float* __restrict__ w3, const float* __restrict__ w4,
    short* __restrict__ w1t, short* __restrict__ w2t,
    short* __restrict__ w3t, short* __restrict__ w4t)
{
    int id = blockIdx.x * 256 + threadIdx.x;
    if (id < 64 * 256) {  // w1,w3: [64][256] -> [256][64]
        int ci = id >> 8, co = id & 255;
        w1t[co * 64 + ci] = f2bf(w1[id]);
        w3t[co * 64 + ci] = f2bf(w3[id]);
    }
    if (id < 128 * 64) {  // w2,w4: [128][64] -> [64][128]
        int ci = id >> 6, co = id & 63;
        w2t[co * 128 + ci] = f2bf(w2[id]);
        w4t[co * 128 + ci] = f2bf(w4[id]);
    }
}

// ---------- K_A: fused LN1 + pw1(MFMA) + dw3x3 + gate + GAP partials ----------
#define UST 136   // LDS row stride (shorts)
__global__ __launch_bounds__(256, 4) void k_a(
    const float* __restrict__ x, const float* __restrict__ ln1g, const float* __restrict__ ln1b,
    const short* __restrict__ w1t, const float* __restrict__ b1,
    const float* __restrict__ dww, const float* __restrict__ dwb,
    short* __restrict__ t, float* __restrict__ gpart)
{
    __shared__ short uh[100 * UST];      // 27200 B
    __shared__ float wlds[9 * 256];      // 9216 B  (dw weights, broadcast-read)
    __shared__ float blds[256];          // 1024 B  (dw bias)
    const int blk = blockIdx.x;
    const int cs  = blk & 1;
    const int txy = blk >> 1;
    const int tx  = txy & 31;
    const int ty  = (txy >> 5) & 31;
    const int b   = txy >> 10;
    const int tid = threadIdx.x;
    const int lane = tid & 63;
    const int wave = tid >> 6;
    const int m    = lane & 15;
    const int quad = lane >> 4;

    // stage dw weights+bias into LDS (coalesced, once per block)
    for (int i = tid; i < 9 * 256; i += 256) wlds[i] = dww[i];
    blds[tid] = dwb[tid];

    // ---- phase 1: u tile via LN1 + pw1 (A = w1 rows, B = ln1(x) cols=pixels)
    for (int tt = wave; tt < 7; tt += 4) {
        int p  = tt * 16 + m;
        int hy = (p * 205) >> 11;          // p/10 for p<112
        int hx = p - hy * 10;
        int gy = ty * 8 + hy - 1, gx = tx * 8 + hx - 1;
        bool pin = (p < 100);
        bool img = pin && gy >= 0 && gy < 256 && gx >= 0 && gx < 256;

        f32x4 f0 = {0,0,0,0}, f1 = {0,0,0,0}, f2 = {0,0,0,0}, f3 = {0,0,0,0};
        if (img) {
            const float* xr = x + ((long)((b * 256 + gy) * 256 + gx)) * 64;
            f0 = *(const f32x4*)(xr + quad * 8);
            f1 = *(const f32x4*)(xr + quad * 8 + 4);
            f2 = *(const f32x4*)(xr + 32 + quad * 8);
            f3 = *(const f32x4*)(xr + 32 + quad * 8 + 4);
        }
        // weight fragment batch (independent of LN chain -> overlaps shuffles)
        short8 wlo[8], whi[8];
#pragma unroll
        for (int cot = 0; cot < 8; ++cot) {
            int cob = (cot < 4) ? (cs * 64 + cot * 16) : (128 + cs * 64 + (cot - 4) * 16);
            wlo[cot] = *(const short8*)(w1t + (cob + m) * 64 + quad * 8);
            whi[cot] = *(const short8*)(w1t + (cob + m) * 64 + 32 + quad * 8);
        }
        float s  = (f0[0]+f0[1]+f0[2]+f0[3]) + (f1[0]+f1[1]+f1[2]+f1[3])
                 + (f2[0]+f2[1]+f2[2]+f2[3]) + (f3[0]+f3[1]+f3[2]+f3[3]);
        float s2 = (f0[0]*f0[0]+f0[1]*f0[1]+f0[2]*f0[2]+f0[3]*f0[3])
                 + (f1[0]*f1[0]+f1[1]*f1[1]+f1[2]*f1[2]+f1[3]*f1[3])
                 + (f2[0]*f2[0]+f2[1]*f2[1]+f2[2]*f2[2]+f2[3]*f2[3])
                 + (f3[0]*f3[0]+f3[1]*f3[1]+f3[2]*f3[2]+f3[3]*f3[3]);
        s  += __shfl_xor(s, 16);  s  += __shfl_xor(s, 32);
        s2 += __shfl_xor(s2, 16); s2 += __shfl_xor(s2, 32);
        float mean = s * 0.015625f;
        float var  = s2 * 0.015625f - mean * mean;
        float rs   = rsqrtf(var + 1e-6f);

        uint4 ua = {0,0,0,0}, ub = {0,0,0,0};
        if (img) {
            f32x4 g0 = *(const f32x4*)(ln1g + quad * 8);
            f32x4 g1 = *(const f32x4*)(ln1g + quad * 8 + 4);
            f32x4 g2 = *(const f32x4*)(ln1g + 32 + quad * 8);
            f32x4 g3 = *(const f32x4*)(ln1g + 32 + quad * 8 + 4);
            f32x4 c0 = *(const f32x4*)(ln1b + quad * 8);
            f32x4 c1 = *(const f32x4*)(ln1b + quad * 8 + 4);
            f32x4 c2 = *(const f32x4*)(ln1b + 32 + quad * 8);
            f32x4 c3 = *(const f32x4*)(ln1b + 32 + quad * 8 + 4);
            ua.x = pkbf2((f0[0]-mean)*rs*g0[0]+c0[0], (f0[1]-mean)*rs*g0[1]+c0[1]);
            ua.y = pkbf2((f0[2]-mean)*rs*g0[2]+c0[2], (f0[3]-mean)*rs*g0[3]+c0[3]);
            ua.z = pkbf2((f1[0]-mean)*rs*g1[0]+c1[0], (f1[1]-mean)*rs*g1[1]+c1[1]);
            ua.w = pkbf2((f1[2]-mean)*rs*g1[2]+c1[2], (f1[3]-mean)*rs*g1[3]+c1[3]);
            ub.x = pkbf2((f2[0]-mean)*rs*g2[0]+c2[0], (f2[1]-mean)*rs*g2[1]+c2[1]);
            ub.y = pkbf2((f2[2]-mean)*rs*g2[2]+c2[2], (f2[3]-mean)*rs*g2[3]+c2[3]);
            ub.z = pkbf2((f3[0]-mean)*rs*g3[0]+c3[0], (f3[1]-mean)*rs*g3[1]+c3[1]);
            ub.w = pkbf2((f3[2]-mean)*rs*g3[2]+c3[2], (f3[3]-mean)*rs*g3[3]+c3[3]);
        }
        short8 a0 = __builtin_bit_cast(short8, ua);
        short8 a1 = __builtin_bit_cast(short8, ub);

#pragma unroll
        for (int cot = 0; cot < 8; ++cot) {
            int cob = (cot < 4) ? (cs * 64 + cot * 16) : (128 + cs * 64 + (cot - 4) * 16);
            f32x4 acc = {0.f, 0.f, 0.f, 0.f};
            acc = __builtin_amdgcn_mfma_f32_16x16x32_bf16(wlo[cot], a0, acc, 0, 0, 0);
            acc = __builtin_amdgcn_mfma_f32_16x16x32_bf16(whi[cot], a1, acc, 0, 0, 0);
            if (pin) {
                f32x4 bv = *(const f32x4*)(b1 + cob + quad * 4);
                uint2 pk = {0u, 0u};
                if (img) {
                    pk.x = pkbf2(acc[0] + bv[0], acc[1] + bv[1]);
                    pk.y = pkbf2(acc[2] + bv[2], acc[3] + bv[3]);
                }
                *(uint2*)&uh[p * UST + cot * 16 + quad * 4] = pk;
            }
        }
    }
    __syncthreads();

    // ---- phase 2: dw3x3 + gate + t store + GAP partials
    const int y = lane >> 3, xx = lane & 7;
    const int cq = wave;                         // 16 gate channels per wave
    const int gc0 = cs * 64 + cq * 16;           // global gate channel base
    const long gpx = ((long)(b * 256 + ty * 8 + y) * 256) + tx * 8 + xx;

    float ac1[16], ac2[16];
#pragma unroll
    for (int i = 0; i < 16; ++i) { ac1[i] = 0.f; ac2[i] = 0.f; }
#pragma unroll
    for (int dy = 0; dy < 3; ++dy)
#pragma unroll
    for (int dx = 0; dx < 3; ++dx) {
        int h = (y + dy) * 10 + (xx + dx);
        short8 u1a = *(const short8*)&uh[h * UST + cq * 16];
        short8 u1b = *(const short8*)&uh[h * UST + cq * 16 + 8];
        short8 u2a = *(const short8*)&uh[h * UST + 64 + cq * 16];
        short8 u2b = *(const short8*)&uh[h * UST + 64 + cq * 16 + 8];
        const float* wp = &wlds[(dy * 3 + dx) * 256 + gc0];   // wave-uniform (broadcast)
        f32x4 wz0 = *(const f32x4*)(wp);
        f32x4 wz1 = *(const f32x4*)(wp + 4);
        f32x4 wz2 = *(const f32x4*)(wp + 8);
        f32x4 wz3 = *(const f32x4*)(wp + 12);
        f32x4 vz0 = *(const f32x4*)(wp + 128);
        f32x4 vz1 = *(const f32x4*)(wp + 132);
        f32x4 vz2 = *(const f32x4*)(wp + 136);
        f32x4 vz3 = *(const f32x4*)(wp + 140);
#pragma unroll
        for (int i = 0; i < 4; ++i) {
            ac1[i]      += bf2f(u1a[i])     * wz0[i];
            ac1[i + 4]  += bf2f(u1a[i + 4]) * wz1[i];
            ac1[i + 8]  += bf2f(u1b[i])     * wz2[i];
            ac1[i + 12] += bf2f(u1b[i + 4]) * wz3[i];
            ac2[i]      += bf2f(u2a[i])     * vz0[i];
            ac2[i + 4]  += bf2f(u2a[i + 4]) * vz1[i];
            ac2[i + 8]  += bf2f(u2b[i])     * vz2[i];
            ac2[i + 12] += bf2f(u2b[i + 4]) * vz3[i];
        }
    }
    f32x4 db1[4], db2[4];
#pragma unroll
    for (int j = 0; j < 4; ++j) {
        db1[j] = *(const f32x4*)&blds[gc0 + j * 4];
        db2[j] = *(const f32x4*)&blds[128 + gc0 + j * 4];
    }
    float tv[16];
#pragma unroll
    for (int i = 0; i < 16; ++i)
        tv[i] = (ac1[i] + db1[i >> 2][i & 3]) * (ac2[i] + db2[i >> 2][i & 3]);
    uint4 s0, s1;
    s0.x = pkbf2(tv[0], tv[1]);   s0.y = pkbf2(tv[2], tv[3]);
    s0.z = pkbf2(tv[4], tv[5]);   s0.w = pkbf2(tv[6], tv[7]);
    s1.x = pkbf2(tv[8], tv[9]);   s1.y = pkbf2(tv[10], tv[11]);
    s1.z = pkbf2(tv[12], tv[13]); s1.w = pkbf2(tv[14], tv[15]);
    *(uint4*)(t + gpx * 128 + gc0)     = s0;
    *(uint4*)(t + gpx * 128 + gc0 + 8) = s1;
#pragma unroll
    for (int i = 0; i < 16; ++i) {
        float v = tv[i];
        v += __shfl_xor(v, 1);  v += __shfl_xor(v, 2);  v += __shfl_xor(v, 4);
        v += __shfl_xor(v, 8);  v += __shfl_xor(v, 16); v += __shfl_xor(v, 32);
        if (lane == 0) gpart[(long)blk * 64 + cq * 16 + i] = v;
    }
}

// ---------- K_R: first-level GAP reduce: gpart[8][1024][128] -> gpart2[8*16][128] ----------
__global__ __launch_bounds__(256) void k_red(
    const float* __restrict__ gpart, float* __restrict__ gpart2)
{
    __shared__ float red[256];
    const int b = blockIdx.x >> 4, g = blockIdx.x & 15;
    const int tid = threadIdx.x;
    const int c = tid & 127, half = tid >> 7;
    const float* gp = gpart + (long)(b * 1024 + g * 64 + half * 32) * 128 + c;
    float s = 0.f;
    for (int i = 0; i < 32; ++i) s += gp[i * 128];
    red[tid] = s;
    __syncthreads();
    if (tid < 128) gpart2[(b * 16 + g) * 128 + c] = red[c] + red[c + 128];
}

// ---------- K_S: final GAP + SCA matmul -> watt[8][128] ----------
__global__ __launch_bounds__(128) void k_sca2(
    const float* __restrict__ gpart2, const float* __restrict__ scaw,
    const float* __restrict__ scab, float* __restrict__ watt)
{
    __shared__ float gl[128];
    const int b = blockIdx.x, c = threadIdx.x;
    float s = 0.f;
#pragma unroll
    for (int g = 0; g < 16; ++g) s += gpart2[(b * 16 + g) * 128 + c];
    gl[c] = s * (1.0f / 65536.0f);
    __syncthreads();
    float acc = scab[c];
    for (int ci = 0; ci < 128; ++ci) acc += gl[ci] * scaw[ci * 128 + c];
    watt[b * 128 + c] = acc;
}

// ---------- K_B: fused pw2 + residual + LN2 + pw3 + gate + pw4 + residual ----------
#define XLST 72    // xn2 LDS row stride (shorts)
#define ZTST 136   // z LDS row stride (shorts)
__global__ __launch_bounds__(256, 4) void k_b(
    const short* __restrict__ t, const float* __restrict__ watt,
    const short* __restrict__ w2t, const float* __restrict__ b2,
    const float* __restrict__ x, const float* __restrict__ beta,
    const float* __restrict__ ln2g, const float* __restrict__ ln2b,
    const short* __restrict__ w3t, const float* __restrict__ b3,
    const short* __restrict__ w4t, const float* __restrict__ b4,
    const float* __restrict__ gamma, float* __restrict__ out)
{
    __shared__ short xl[4][16 * XLST];   // 9216 B
    __shared__ short zt[4][16 * ZTST];   // 17408 B
    const int lane = threadIdx.x & 63;
    const int wave = threadIdx.x >> 6;
    const int m = lane & 15, quad = lane >> 4;
    const long px0 = (long)blockIdx.x * 64 + wave * 16;
    const int b = (int)(px0 >> 16);
    const float* wa = watt + b * 128;

    // front loads: t frags + x residual (all independent, issued together)
    const short* tr = t + (px0 + m) * 128;
    short8 tf[4];
#pragma unroll
    for (int kh = 0; kh < 4; ++kh) tf[kh] = *(const short8*)(tr + kh * 32 + quad * 8);
    f32x4 xv[4];
#pragma unroll
    for (int nt = 0; nt < 4; ++nt)
        xv[nt] = *(const f32x4*)(x + (px0 + m) * 64 + nt * 16 + quad * 4);

    // B-frags: t * watt (bf16 repack)
    short8 bfr[4];
#pragma unroll
    for (int kh = 0; kh < 4; ++kh) {
        f32x4 w0  = *(const f32x4*)(wa + kh * 32 + quad * 8);
        f32x4 w1v = *(const f32x4*)(wa + kh * 32 + quad * 8 + 4);
        uint4 u;
        u.x = pkbf2(bf2f(tf[kh][0]) * w0[0],  bf2f(tf[kh][1]) * w0[1]);
        u.y = pkbf2(bf2f(tf[kh][2]) * w0[2],  bf2f(tf[kh][3]) * w0[3]);
        u.z = pkbf2(bf2f(tf[kh][4]) * w1v[0], bf2f(tf[kh][5]) * w1v[1]);
        u.w = pkbf2(bf2f(tf[kh][6]) * w1v[2], bf2f(tf[kh][7]) * w1v[3]);
        bfr[kh] = __builtin_bit_cast(short8, u);
    }
    // pw2 (double-buffered weight frags)
    f32x4 acc2[4];
    short8 wb2[2][4];
#pragma unroll
    for (int kh = 0; kh < 4; ++kh)
        wb2[0][kh] = *(const short8*)(w2t + m * 128 + kh * 32 + quad * 8);
#pragma unroll
    for (int nt = 0; nt < 4; ++nt) {
        if (nt < 3) {
#pragma unroll
            for (int kh = 0; kh < 4; ++kh)
                wb2[(nt + 1) & 1][kh] =
                    *(const short8*)(w2t + ((nt + 1) * 16 + m) * 128 + kh * 32 + quad * 8);
        }
        f32x4 a = {0.f, 0.f, 0.f, 0.f};
#pragma unroll
        for (int kh = 0; kh < 4; ++kh)
            a = __builtin_amdgcn_mfma_f32_16x16x32_bf16(wb2[nt & 1][kh], bfr[kh], a, 0, 0, 0);
        acc2[nt] = a;
    }
    // x1 = x + (pw2+b2)*beta   (lane holds co=nt*16+quad*4+r, px=m)
    float x1v[4][4];
#pragma unroll
    for (int nt = 0; nt < 4; ++nt) {
        int cob = nt * 16 + quad * 4;
        f32x4 bb = *(const f32x4*)(b2 + cob);
        f32x4 be = *(const f32x4*)(beta + cob);
#pragma unroll
        for (int r = 0; r < 4; ++r)
            x1v[nt][r] = xv[nt][r] + (acc2[nt][r] + bb[r]) * be[r];
    }
    // LN2 over 64 co
    float s = 0.f, s2 = 0.f;
#pragma unroll
    for (int nt = 0; nt < 4; ++nt)
#pragma unroll
        for (int r = 0; r < 4; ++r) { s += x1v[nt][r]; s2 += x1v[nt][r] * x1v[nt][r]; }
    s  += __shfl_xor(s, 16);  s  += __shfl_xor(s, 32);
    s2 += __shfl_xor(s2, 16); s2 += __shfl_xor(s2, 32);
    float mean = s * 0.015625f;
    float var  = s2 * 0.015625f - mean * mean;
    float rs   = rsqrtf(var + 1e-6f);
#pragma unroll
    for (int nt = 0; nt < 4; ++nt) {
        int cob = nt * 16 + quad * 4;
        f32x4 gg = *(const f32x4*)(ln2g + cob);
        f32x4 cc = *(const f32x4*)(ln2b + cob);
        uint2 pk;
        pk.x = pkbf2((x1v[nt][0] - mean) * rs * gg[0] + cc[0],
                     (x1v[nt][1] - mean) * rs * gg[1] + cc[1]);
        pk.y = pkbf2((x1v[nt][2] - mean) * rs * gg[2] + cc[2],
                     (x1v[nt][3] - mean) * rs * gg[3] + cc[3]);
        *(uint2*)&xl[wave][m * XLST + cob] = pk;
    }
    WAVE_LDS_FENCE();    // xl is per-wave private: wave-lockstep + lgkmcnt(0) suffices
    // pw3 (paired tiles for gate), double-buffered weights
    short8 xb0 = *(const short8*)&xl[wave][m * XLST + quad * 8];
    short8 xb1 = *(const short8*)&xl[wave][m * XLST + 32 + quad * 8];
    short8 wb3[2][4];
#pragma unroll
    for (int i = 0; i < 2; ++i) {
        wb3[0][2 * i]     = *(const short8*)(w3t + (128 * i + m) * 64 + quad * 8);
        wb3[0][2 * i + 1] = *(const short8*)(w3t + (128 * i + m) * 64 + 32 + quad * 8);
    }
#pragma unroll
    for (int pg = 0; pg < 8; ++pg) {
        if (pg < 7) {
            int nb = (pg + 1) & 1;
#pragma unroll
            for (int i = 0; i < 2; ++i) {
                wb3[nb][2 * i]     = *(const short8*)(w3t + (128 * i + (pg + 1) * 16 + m) * 64 + quad * 8);
                wb3[nb][2 * i + 1] = *(const short8*)(w3t + (128 * i + (pg + 1) * 16 + m) * 64 + 32 + quad * 8);
            }
        }
        f32x4 aA = {0.f,0.f,0.f,0.f}, aB = {0.f,0.f,0.f,0.f};
        aA = __builtin_amdgcn_mfma_f32_16x16x32_bf16(wb3[pg & 1][0], xb0, aA, 0, 0, 0);
        aA = __builtin_amdgcn_mfma_f32_16x16x32_bf16(wb3[pg & 1][1], xb1, aA, 0, 0, 0);
        aB = __builtin_amdgcn_mfma_f32_16x16x32_bf16(wb3[pg & 1][2], xb0, aB, 0, 0, 0);
        aB = __builtin_amdgcn_mfma_f32_16x16x32_bf16(wb3[pg & 1][3], xb1, aB, 0, 0, 0);
        int cb = pg * 16 + quad * 4;
        f32x4 bA = *(const f32x4*)(b3 + cb);
        f32x4 bB = *(const f32x4*)(b3 + 128 + cb);
        uint2 pk;
        pk.x = pkbf2((aA[0] + bA[0]) * (aB[0] + bB[0]), (aA[1] + bA[1]) * (aB[1] + bB[1]));
        pk.y = pkbf2((aA[2] + bA[2]) * (aB[2] + bB[2]), (aA[3] + bA[3]) * (aB[3] + bB[3]));
        *(uint2*)&zt[wave][m * ZTST + cb] = pk;
    }
    WAVE_LDS_FENCE();    // zt is per-wave private
    // pw4 (double-buffered weights)
    short8 zb[4];
#pragma unroll
    for (int kh = 0; kh < 4; ++kh)
        zb[kh] = *(const short8*)&zt[wave][m * ZTST + kh * 32 + quad * 8];
    short8 wb4[2][4];
#pragma unroll
    for (int kh = 0; kh < 4; ++kh)
        wb4[0][kh] = *(const short8*)(w4t + m * 128 + kh * 32 + quad * 8);
#pragma unroll
    for (int nt = 0; nt < 4; ++nt) {
        if (nt < 3) {
#pragma unroll
            for (int kh = 0; kh < 4; ++kh)
                wb4[(nt + 1) & 1][kh] =
                    *(const short8*)(w4t + ((nt + 1) * 16 + m) * 128 + kh * 32 + quad * 8);
        }
        f32x4 a = {0.f, 0.f, 0.f, 0.f};
#pragma unroll
        for (int kh = 0; kh < 4; ++kh)
            a = __builtin_amdgcn_mfma_f32_16x16x32_bf16(wb4[nt & 1][kh], zb[kh], a, 0, 0, 0);
        int cob = nt * 16 + quad * 4;
        f32x4 bb = *(const f32x4*)(b4 + cob);
        f32x4 gm = *(const f32x4*)(gamma + cob);
        f32x4 o;
#pragma unroll
        for (int r = 0; r < 4; ++r)
            o[r] = x1v[nt][r] + (a[r] + bb[r]) * gm[r];
        *(f32x4*)(out + (px0 + m) * 64 + cob) = o;
    }
}

// ---------- launch ----------
extern "C" void kernel_launch(void* const* d_in, const int* in_sizes, int n_in,
                              void* d_out, int out_size, void* d_ws, size_t ws_size,
                              hipStream_t stream) {
    (void)in_sizes; (void)n_in; (void)out_size; (void)ws_size;
    const float* x    = (const float*)d_in[0];
    const float* ln1g = (const float*)d_in[1];
    const float* ln1b = (const float*)d_in[2];
    const float* pw1w = (const float*)d_in[3];
    const float* pw1b = (const float*)d_in[4];
    const float* dww  = (const float*)d_in[5];
    const float* dwb  = (const float*)d_in[6];
    const float* scaw = (const float*)d_in[7];
    const float* scab = (const float*)d_in[8];
    const float* pw2w = (const float*)d_in[9];
    const float* pw2b = (const float*)d_in[10];
    const float* beta = (const float*)d_in[11];
    const float* ln2g = (const float*)d_in[12];
    const float* ln2b = (const float*)d_in[13];
    const float* pw3w = (const float*)d_in[14];
    const float* pw3b = (const float*)d_in[15];
    const float* pw4w = (const float*)d_in[16];
    const float* pw4b = (const float*)d_in[17];
    const float* gamma= (const float*)d_in[18];

    char* ws = (char*)d_ws;
    short* w1t = (short*)(ws + OFF_W1T);
    short* w2t = (short*)(ws + OFF_W2T);
    short* w3t = (short*)(ws + OFF_W3T);
    short* w4t = (short*)(ws + OFF_W4T);
    float* watt = (float*)(ws + OFF_WATT);
    float* gpart = (float*)(ws + OFF_GPART);
    float* gpart2 = (float*)(ws + OFF_GPART2);
    short* t   = (short*)(ws + OFF_T);
    float* out = (float*)d_out;

    k_prep<<<64, 256, 0, stream>>>(pw1w, pw2w, pw3w, pw4w, w1t, w2t, w3t, w4t);
    k_a<<<16384, 256, 0, stream>>>(x, ln1g, ln1b, w1t, pw1b, dww, dwb, t, gpart);
    k_red<<<128, 256, 0, stream>>>(gpart, gpart2);
    k_sca2<<<8, 128, 0, stream>>>(gpart2, scaw, scab, watt);
    k_b<<<8192, 256, 0, stream>>>(t, watt, w2t, pw2b, x, beta, ln2g, ln2b,
                                  w3t, pw3b, w4t, pw4b, gamma, out);
}